// Round 3
// baseline (1604.573 us; speedup 1.0000x reference)
//
#include <hip/hip_runtime.h>
#include <hip/hip_bf16.h>
#include <math.h>

#define IMG 48
#define NPIX 2304
#define CH 128
#define NHEADS 8
#define HDIM 16
#define QK_SCALE 0.14433756729740643f   // 1/sqrt(48)
#define LN1E4 9.210340371976184f        // ln(10000)

// =====================================================================
// Kernel 1: complex conv for q,k,v  + bias + rotary + polar transform.
// Block: 256 threads, handles channel pair (co0, co0+1) x 6-row tile.
// Grid: (8 tiles, 64 pairs).
// Outputs (ws, [h][n][d] layout, f32):
//   qm, qp, km, kp, and interleaved v: [h][n][d][2] = (vm, vp)
// =====================================================================
__global__ __launch_bounds__(256) void conv_qkv_kernel(
    const float* __restrict__ xr_g, const float* __restrict__ xi_g,
    const float* __restrict__ wq_r, const float* __restrict__ wq_i,
    const float* __restrict__ bq_r, const float* __restrict__ bq_i,
    const float* __restrict__ wk_r, const float* __restrict__ wk_i,
    const float* __restrict__ bk_r, const float* __restrict__ bk_i,
    const float* __restrict__ wv_r, const float* __restrict__ wv_i,
    const float* __restrict__ bv_r, const float* __restrict__ bv_i,
    float* __restrict__ qm_ws, float* __restrict__ qp_ws,
    float* __restrict__ km_ws, float* __restrict__ kp_ws,
    float* __restrict__ vmp_ws)
{
    __shared__ float wlds[CH * 9 * 12];   // [ci][tap][12]: (c0:qr,qi,kr,ki,vr,vi, c1:...)
    __shared__ float xlds[2][8][50];      // padded: rows y0-1..y0+6, cols -1..48

    const int tid  = threadIdx.x;
    const int tile = blockIdx.x;          // 0..7 (6 rows each)
    const int pair = blockIdx.y;          // 0..63
    const int co0  = pair * 2;
    const int y0   = tile * 6;

    // ---- stage weights into LDS (global-coalesced) ----
    {
        const float* wptr[6] = { wq_r, wq_i, wk_r, wk_i, wv_r, wv_i };
        for (int k12 = 0; k12 < 12; ++k12) {
            const int c = k12 / 6, cv = k12 % 6;
            const float* src = wptr[cv] + (co0 + c) * (CH * 9);
            for (int i = tid; i < CH * 9; i += 256)
                wlds[i * 12 + k12] = src[i];
        }
    }

    float acc[2][12];
    #pragma unroll
    for (int j = 0; j < 2; ++j)
        #pragma unroll
        for (int q = 0; q < 12; ++q) acc[j][q] = 0.f;

    for (int ci = 0; ci < CH; ++ci) {
        __syncthreads();
        // stage padded x plane rows
        for (int i = tid; i < 2 * 8 * 50; i += 256) {
            const int comp = i / 400;
            const int rem  = i % 400;
            const int row  = rem / 50;
            const int col  = rem % 50;
            const int gy = y0 - 1 + row;
            const int gx = col - 1;
            float v = 0.f;
            if ((unsigned)gy < IMG && (unsigned)gx < IMG)
                v = (comp ? xi_g : xr_g)[ci * NPIX + gy * IMG + gx];
            xlds[comp][row][col] = v;
        }
        __syncthreads();

        const float* wrow = &wlds[ci * 108];
        for (int tap = 0; tap < 9; ++tap) {
            const int ky = tap / 3, kx = tap % 3;
            const float4 w0 = *(const float4*)&wrow[tap * 12 + 0];
            const float4 w1 = *(const float4*)&wrow[tap * 12 + 4];
            const float4 w2 = *(const float4*)&wrow[tap * 12 + 8];
            #pragma unroll
            for (int j = 0; j < 2; ++j) {
                const int px = tid + j * 256;
                if (px < 288) {
                    const int row = px / 48, col = px % 48;
                    const float xr = xlds[0][row + ky][col + kx];
                    const float xi = xlds[1][row + ky][col + kx];
                    float* a = acc[j];
                    a[0]  = fmaf(xr, w0.x, a[0]);  a[0]  = fmaf(-xi, w0.y, a[0]);
                    a[1]  = fmaf(xr, w0.y, a[1]);  a[1]  = fmaf( xi, w0.x, a[1]);
                    a[2]  = fmaf(xr, w0.z, a[2]);  a[2]  = fmaf(-xi, w0.w, a[2]);
                    a[3]  = fmaf(xr, w0.w, a[3]);  a[3]  = fmaf( xi, w0.z, a[3]);
                    a[4]  = fmaf(xr, w1.x, a[4]);  a[4]  = fmaf(-xi, w1.y, a[4]);
                    a[5]  = fmaf(xr, w1.y, a[5]);  a[5]  = fmaf( xi, w1.x, a[5]);
                    a[6]  = fmaf(xr, w1.z, a[6]);  a[6]  = fmaf(-xi, w1.w, a[6]);
                    a[7]  = fmaf(xr, w1.w, a[7]);  a[7]  = fmaf( xi, w1.z, a[7]);
                    a[8]  = fmaf(xr, w2.x, a[8]);  a[8]  = fmaf(-xi, w2.y, a[8]);
                    a[9]  = fmaf(xr, w2.y, a[9]);  a[9]  = fmaf( xi, w2.x, a[9]);
                    a[10] = fmaf(xr, w2.z, a[10]); a[10] = fmaf(-xi, w2.w, a[10]);
                    a[11] = fmaf(xr, w2.w, a[11]); a[11] = fmaf( xi, w2.z, a[11]);
                }
            }
        }
    }

    // ---- epilogue: bias, rotary (q,k), polar, store ----
    const int h  = co0 >> 4;
    const int d0 = co0 & 15;   // even
    const float bqr0 = bq_r[co0],     bqi0 = bq_i[co0];
    const float bkr0 = bk_r[co0],     bki0 = bk_i[co0];
    const float bvr0 = bv_r[co0],     bvi0 = bv_i[co0];
    const float bqr1 = bq_r[co0 + 1], bqi1 = bq_i[co0 + 1];
    const float bkr1 = bk_r[co0 + 1], bki1 = bk_i[co0 + 1];
    const float bvr1 = bv_r[co0 + 1], bvi1 = bv_i[co0 + 1];
    const float inv_freq = expf(-(float)d0 * (LN1E4 / 16.0f));

    #pragma unroll
    for (int j = 0; j < 2; ++j) {
        const int px = tid + j * 256;
        if (px < 288) {
            const int n = y0 * IMG + px;
            const float ang = (float)n * inv_freq;
            const float cs = cosf(ang), sn = sinf(ang);
            float* a = acc[j];
            float qre = a[0] + bqr0, qie = a[1] + bqi0;
            float kre = a[2] + bkr0, kie = a[3] + bki0;
            float vre = a[4] + bvr0, vie = a[5] + bvi0;
            float qro = a[6] + bqr1, qio = a[7] + bqi1;
            float kro = a[8] + bkr1, kio = a[9] + bki1;
            float vro = a[10] + bvr1, vio = a[11] + bvi1;
            float t;
            t = qre * cs - qro * sn; qro = qro * cs + qre * sn; qre = t;
            t = qie * cs - qio * sn; qio = qio * cs + qie * sn; qie = t;
            t = kre * cs - kro * sn; kro = kro * cs + kre * sn; kre = t;
            t = kie * cs - kio * sn; kio = kio * cs + kie * sn; kie = t;

            const int base = (h * NPIX + n) * HDIM + d0;
            float2 f2;
            f2.x = sqrtf(qre * qre + qie * qie);
            f2.y = sqrtf(qro * qro + qio * qio);
            *(float2*)&qm_ws[base] = f2;
            f2.x = atan2f(qie, qre);
            f2.y = atan2f(qio, qro);
            *(float2*)&qp_ws[base] = f2;
            f2.x = sqrtf(kre * kre + kie * kie);
            f2.y = sqrtf(kro * kro + kio * kio);
            *(float2*)&km_ws[base] = f2;
            f2.x = atan2f(kie, kre);
            f2.y = atan2f(kio, kro);
            *(float2*)&kp_ws[base] = f2;
            float4 v4;
            v4.x = sqrtf(vre * vre + vie * vie);
            v4.y = atan2f(vie, vre);
            v4.z = sqrtf(vro * vro + vio * vio);
            v4.w = atan2f(vio, vro);
            *(float4*)&vmp_ws[base * 2] = v4;
        }
    }
}

// =====================================================================
// Kernel 2: fused attention (f32 softmax end-to-end, f32 outputs).
// Block: 256 threads = 8 rows (r = tid>>5) x 32 lanes (ml = tid&31).
// Grid: 2304 blocks; h = bid & 7 (XCD L2 locality), row tile = (bid>>3)*8.
// =====================================================================
__global__ __launch_bounds__(256) void attn_kernel(
    const float* __restrict__ qm_ws, const float* __restrict__ qp_ws,
    const float* __restrict__ km_ws, const float* __restrict__ kp_ws,
    const float* __restrict__ vmp_ws,
    float* __restrict__ qkm_out, float* __restrict__ qkp_out,
    float* __restrict__ ar_ws, float* __restrict__ ai_ws)
{
    __shared__ float plds[8][NPIX + 1];   // f32 scores/probs, 73,760 B

    const int tid = threadIdx.x;
    const int bid = blockIdx.x;           // 0..2303
    const int h   = bid & 7;
    const int r0  = (bid >> 3) * 8;
    const int r   = tid >> 5;             // 0..7
    const int ml  = tid & 31;             // lane within row group
    const int n   = r0 + r;               // query row

    // q row fragments in registers (broadcast: 32 lanes share r)
    float qmr[16], qpr[16];
    {
        const float* qmp = qm_ws + ((size_t)h * NPIX + n) * HDIM;
        const float* qpp = qp_ws + ((size_t)h * NPIX + n) * HDIM;
        #pragma unroll
        for (int d = 0; d < 16; d += 4) {
            const float4 a = *(const float4*)&qmp[d];
            const float4 b = *(const float4*)&qpp[d];
            qmr[d] = a.x; qmr[d + 1] = a.y; qmr[d + 2] = a.z; qmr[d + 3] = a.w;
            qpr[d] = b.x; qpr[d + 1] = b.y; qpr[d + 2] = b.z; qpr[d + 3] = b.w;
        }
    }

    // ---- pass 1: scores ----
    float lmax = 0.f;   // |s| >= 0
    for (int g = 0; g < 72; ++g) {
        const int m = ml + (g << 5);
        const float* kmp = km_ws + ((size_t)h * NPIX + m) * HDIM;
        const float* kpp = kp_ws + ((size_t)h * NPIX + m) * HDIM;
        float sm = 0.f, sp = 0.f;
        #pragma unroll
        for (int d = 0; d < 16; d += 4) {
            const float4 a = *(const float4*)&kmp[d];
            const float4 b = *(const float4*)&kpp[d];
            sm = fmaf(qmr[d], a.x, sm);     sm = fmaf(qmr[d + 1], a.y, sm);
            sm = fmaf(qmr[d + 2], a.z, sm); sm = fmaf(qmr[d + 3], a.w, sm);
            sp = fmaf(qpr[d], b.x, sp);     sp = fmaf(qpr[d + 1], b.y, sp);
            sp = fmaf(qpr[d + 2], b.z, sp); sp = fmaf(qpr[d + 3], b.w, sp);
        }
        sm *= QK_SCALE; sp *= QK_SCALE;
        const size_t ob = ((size_t)h * NPIX + n) * NPIX + m;
        qkm_out[ob] = sm;
        qkp_out[ob] = sp;
        const float as = fabsf(sm);
        plds[r][m] = as;
        lmax = fmaxf(lmax, as);
    }
    #pragma unroll
    for (int mask = 1; mask < 32; mask <<= 1)
        lmax = fmaxf(lmax, __shfl_xor(lmax, mask));

    // ---- pass 2: exp + row sum (each thread touches only its own m's) ----
    float lsum = 0.f;
    for (int g = 0; g < 72; ++g) {
        const int m = ml + (g << 5);
        const float p = expf(plds[r][m] - lmax);
        lsum += p;
        plds[r][m] = p;
    }
    #pragma unroll
    for (int mask = 1; mask < 32; mask <<= 1)
        lsum += __shfl_xor(lsum, mask);
    __syncthreads();   // all p values visible to the whole row group

    // ---- pass 3: P.V, thread = (r, half, d) ----
    const int d  = ml & 15;
    const int hf = ml >> 4;
    float accm = 0.f, accp = 0.f;
    const float* vb = vmp_ws + (size_t)h * NPIX * 32 + d * 2;
    for (int g = 0; g < 1152; ++g) {
        const int m = (g << 1) + hf;
        const float p = plds[r][m];
        const float2 v2 = *(const float2*)&vb[(size_t)m * 32];
        accm = fmaf(p, v2.x, accm);
        accp = fmaf(p, v2.y, accp);
    }
    accm += __shfl_xor(accm, 16);
    accp += __shfl_xor(accp, 16);
    if (hf == 0) {
        const float om = accm / lsum;
        const float op = accp / lsum;
        const int c = h * HDIM + d;
        ar_ws[c * NPIX + n] = om * cosf(op);
        ai_ws[c * NPIX + n] = om * sinf(op);
    }
}

// =====================================================================
// Kernel 3: output complex conv from a_r/a_i (NCHW f32 in ws) -> o_r,o_i f32
// =====================================================================
__global__ __launch_bounds__(256) void conv_o_kernel(
    const float* __restrict__ ar_g, const float* __restrict__ ai_g,
    const float* __restrict__ wo_r, const float* __restrict__ wo_i,
    const float* __restrict__ bo_r, const float* __restrict__ bo_i,
    float* __restrict__ or_out, float* __restrict__ oi_out)
{
    __shared__ float wlds[CH * 9 * 4];    // [ci][tap][4]: wr0, wi0, wr1, wi1
    __shared__ float xlds[2][8][50];

    const int tid  = threadIdx.x;
    const int tile = blockIdx.x;          // 0..7
    const int pair = blockIdx.y;          // 0..63
    const int co0  = pair * 2;
    const int y0   = tile * 6;

    {
        for (int k4 = 0; k4 < 4; ++k4) {
            const int c = k4 >> 1;
            const float* src = ((k4 & 1) ? wo_i : wo_r) + (co0 + c) * (CH * 9);
            for (int i = tid; i < CH * 9; i += 256)
                wlds[i * 4 + k4] = src[i];
        }
    }

    float acc[2][4];
    #pragma unroll
    for (int j = 0; j < 2; ++j)
        #pragma unroll
        for (int q = 0; q < 4; ++q) acc[j][q] = 0.f;

    for (int ci = 0; ci < CH; ++ci) {
        __syncthreads();
        for (int i = tid; i < 2 * 8 * 50; i += 256) {
            const int comp = i / 400;
            const int rem  = i % 400;
            const int row  = rem / 50;
            const int col  = rem % 50;
            const int gy = y0 - 1 + row;
            const int gx = col - 1;
            float v = 0.f;
            if ((unsigned)gy < IMG && (unsigned)gx < IMG)
                v = (comp ? ai_g : ar_g)[ci * NPIX + gy * IMG + gx];
            xlds[comp][row][col] = v;
        }
        __syncthreads();

        const float* wrow = &wlds[ci * 36];
        for (int tap = 0; tap < 9; ++tap) {
            const int ky = tap / 3, kx = tap % 3;
            const float4 w = *(const float4*)&wrow[tap * 4];
            #pragma unroll
            for (int j = 0; j < 2; ++j) {
                const int px = tid + j * 256;
                if (px < 288) {
                    const int row = px / 48, col = px % 48;
                    const float ar = xlds[0][row + ky][col + kx];
                    const float ai = xlds[1][row + ky][col + kx];
                    float* a = acc[j];
                    a[0] = fmaf(ar, w.x, a[0]); a[0] = fmaf(-ai, w.y, a[0]);
                    a[1] = fmaf(ar, w.y, a[1]); a[1] = fmaf( ai, w.x, a[1]);
                    a[2] = fmaf(ar, w.z, a[2]); a[2] = fmaf(-ai, w.w, a[2]);
                    a[3] = fmaf(ar, w.w, a[3]); a[3] = fmaf( ai, w.z, a[3]);
                }
            }
        }
    }

    const float br0 = bo_r[co0],     bi0 = bo_i[co0];
    const float br1 = bo_r[co0 + 1], bi1 = bo_i[co0 + 1];
    #pragma unroll
    for (int j = 0; j < 2; ++j) {
        const int px = tid + j * 256;
        if (px < 288) {
            const int n = y0 * IMG + px;
            or_out[co0 * NPIX + n]       = acc[j][0] + br0;
            oi_out[co0 * NPIX + n]       = acc[j][1] + bi0;
            or_out[(co0 + 1) * NPIX + n] = acc[j][2] + br1;
            oi_out[(co0 + 1) * NPIX + n] = acc[j][3] + bi1;
        }
    }
}

// =====================================================================
extern "C" void kernel_launch(void* const* d_in, const int* in_sizes, int n_in,
                              void* d_out, int out_size, void* d_ws, size_t ws_size,
                              hipStream_t stream)
{
    const float* xr   = (const float*)d_in[0];
    const float* xi   = (const float*)d_in[1];
    const float* wq_r = (const float*)d_in[2];
    const float* wq_i = (const float*)d_in[3];
    const float* bq_r = (const float*)d_in[4];
    const float* bq_i = (const float*)d_in[5];
    const float* wk_r = (const float*)d_in[6];
    const float* wk_i = (const float*)d_in[7];
    const float* bk_r = (const float*)d_in[8];
    const float* bk_i = (const float*)d_in[9];
    const float* wv_r = (const float*)d_in[10];
    const float* wv_i = (const float*)d_in[11];
    const float* bv_r = (const float*)d_in[12];
    const float* bv_i = (const float*)d_in[13];
    const float* wo_r = (const float*)d_in[14];
    const float* wo_i = (const float*)d_in[15];
    const float* bo_r = (const float*)d_in[16];
    const float* bo_i = (const float*)d_in[17];

    float* ws  = (float*)d_ws;
    float* qm  = ws;
    float* qp  = qm  + 294912;
    float* km  = qp  + 294912;
    float* kp  = km  + 294912;
    float* vmp = kp  + 294912;        // 589824 floats (interleaved vm,vp)
    float* ar  = vmp + 589824;
    float* ai  = ar  + 294912;

    float* out = (float*)d_out;       // f32: reference output dtype
    float* o_r = out;
    float* o_i = out + 294912;
    float* qkm = out + 589824;
    float* qkp = qkm + 42467328;

    conv_qkv_kernel<<<dim3(8, 64), 256, 0, stream>>>(
        xr, xi, wq_r, wq_i, bq_r, bq_i, wk_r, wk_i, bk_r, bk_i,
        wv_r, wv_i, bv_r, bv_i, qm, qp, km, kp, vmp);

    attn_kernel<<<dim3(2304), 256, 0, stream>>>(
        qm, qp, km, kp, vmp, qkm, qkp, ar, ai);

    conv_o_kernel<<<dim3(8, 64), 256, 0, stream>>>(
        ar, ai, wo_r, wo_i, bo_r, bo_i, o_r, o_i);
}